// Round 20
// baseline (124.090 us; speedup 1.0000x reference)
//
#include <hip/hip_runtime.h>

#define NEARZERO 1e-5f
#define RLEN 15
#define LOG2E 1.4426950408889634f

struct __attribute__((packed, aligned(4))) F3 { float x, y, z; };
static __device__ __forceinline__ F3 ldo(const char* base, unsigned voff) {
    return *reinterpret_cast<const F3*>(base + voff);
}

struct Par { float FC, invFC, invLPFC, K1, K2, PERC, UZL, TT, CFMAX, CFRC, CWH, C; };

// snow+soil of t=0 (capillary from initial SLZ)
__device__ __forceinline__ void ab_step0(
    const F3 f, const F3 d3, const Par& pr,
    float& SP, float& MW, float& SM, float& SLZ,
    float& rxP, float& k0P)
{
    const float cs = pr.C * SLZ;
    const float dT   = f.y - pr.TT;
    const float RAIN = (dT >= 0.0f) ? f.x : 0.0f;
    SP += f.x - RAIN;
    const float melt = __builtin_amdgcn_fmed3f(pr.CFMAX * dT, 0.0f, SP);
    MW += melt;  SP -= melt;
    const float refr = __builtin_amdgcn_fmed3f(pr.CFRC * (0.0f - dT), 0.0f, MW);
    SP += refr;  MW -= refr;
    const float tosoil = fmaxf(fmaf(-pr.CWH, SP, MW), 0.0f);
    MW -= tosoil;
    const float sw = fminf(exp2f(fmaf(d3.x, 5.0f, 1.0f) * __log2f(SM * pr.invFC)), 1.0f);
    const float rt = RAIN + tosoil;
    const float rc = rt * sw;
    SM = fmaf(rt, 1.0f - sw, SM);
    const float ex = fmaxf(SM - pr.FC, 0.0f);
    SM = fminf(SM, pr.FC);
    const float ef = fminf(exp2f(fmaf(d3.z, 4.7f, 0.3f) * __log2f(SM * pr.invLPFC)), 1.0f);
    SM = fmaxf(SM - f.z * ef, NEARZERO);
    const float cap = cs * (1.0f - fminf(SM * pr.invFC, 1.0f));
    SM  = fmaxf(SM + cap, NEARZERO);
    SLZ = fmaxf(SLZ - cap, NEARZERO);
    rxP = rc + ex;
    k0P = fmaf(d3.y, 0.85f, 0.05f);
}

// wave0 fused step m: finish(m) [zones] -> Qs to LDS; ab(m+1). No FIR, no store.
template<int I, int B>
__device__ __forceinline__ void fused0(
    const F3 f, const F3 d3, const Par& pr,
    float& SP, float& MW, float& SM, float& SUZ, float& SLZ,
    float& rxP, float& k0P,
    float (*qbuf)[RLEN][64], int lane)
{
    const float t1 = __log2f(SM * pr.invFC);             // trans #1
    // snow(m+1)
    const float dT   = f.y - pr.TT;
    const float RAIN = (dT >= 0.0f) ? f.x : 0.0f;
    SP += f.x - RAIN;
    const float melt = __builtin_amdgcn_fmed3f(pr.CFMAX * dT, 0.0f, SP);
    MW += melt;  SP -= melt;
    const float refr = __builtin_amdgcn_fmed3f(pr.CFRC * (0.0f - dT), 0.0f, MW);
    SP += refr;  MW -= refr;
    const float tosoil = fmaxf(fmaf(-pr.CWH, SP, MW), 0.0f);
    MW -= tosoil;
    // upper zone of m
    SUZ += rxP;
    const float PERCv = fminf(SUZ, pr.PERC);
    SUZ -= PERCv;
    const float Q0 = k0P * fmaxf(SUZ - pr.UZL, 0.0f);
    SUZ -= Q0;
    const float Q1 = pr.K1 * SUZ;
    SUZ -= Q1;
    const float sw = fminf(exp2f(fmaf(d3.x, 5.0f, 1.0f) * t1), 1.0f);  // trans #2
    const float rt = RAIN + tosoil;
    // lower zone of m
    SLZ += PERCv;
    const float Q2 = pr.K2 * SLZ;
    SLZ -= Q2;
    const float Qs = Q0 + Q1 + Q2;
    const float cs = pr.C * SLZ;
    qbuf[B][I][lane] = Qs;               // hand Qs(m) to the FIR wave
    // soil of m+1
    const float rc = rt * sw;
    SM = fmaf(rt, 1.0f - sw, SM);
    const float ex = fmaxf(SM - pr.FC, 0.0f);
    SM = fminf(SM, pr.FC);
    const float t2 = __log2f(SM * pr.invLPFC);           // trans #3
    const float ef = fminf(exp2f(fmaf(d3.z, 4.7f, 0.3f) * t2), 1.0f);  // trans #4
    SM = fmaxf(SM - f.z * ef, NEARZERO);
    const float cap = cs * (1.0f - fminf(SM * pr.invFC, 1.0f));
    SM  = fmaxf(SM + cap, NEARZERO);
    SLZ = fmaxf(SLZ - cap, NEARZERO);
    rxP = rc + ex;
    k0P = fmaf(d3.y, 0.85f, 0.05f);
}

__global__ __launch_bounds__(128, 1)
void hbv_kernel(const float* __restrict__ forcing,   // (365,G,3)
                const float* __restrict__ dynr,      // (365,G,3)
                const float* __restrict__ statr,     // (G,15)
                float* __restrict__ out,             // (365,G)
                int G)
{
    // Qs handoff ring: [buf][slot][lane]; group j (15 steps) -> buf j&1.
    __shared__ float qbuf[2][RLEN][64];              // 7680 B

    const int lane = threadIdx.x & 63;
    const int wave = threadIdx.x >> 6;
    const int g  = blockIdx.x * 64 + lane;
    const int gc = (g < G) ? g : (G - 1);            // clamp loads; stores guarded

    if (wave == 0) {
        // ===== wave 0: HBV spine (zones+snow+soil), Qs -> LDS =====
        const float* sp = statr + (size_t)gc * 15;
        Par pr;
        pr.FC    = fmaf(sp[0], 950.0f, 50.0f);
        pr.K1    = fmaf(sp[1], 0.49f, 0.01f);
        pr.K2    = fmaf(sp[2], 0.199f, 0.001f);
        const float parLP = fmaf(sp[3], 0.8f, 0.2f);
        pr.PERC  = sp[4] * 10.0f;
        pr.UZL   = sp[5] * 100.0f;
        pr.TT    = fmaf(sp[6], 5.0f, -2.5f);
        pr.CFMAX = fmaf(sp[7], 9.5f, 0.5f);
        pr.CFRC  = (sp[8] * 0.1f) * pr.CFMAX;
        pr.CWH   = sp[9] * 0.2f;
        pr.C     = sp[10];
        pr.invFC   = 1.0f / pr.FC;
        pr.invLPFC = 1.0f / (parLP * pr.FC);

        float SP_ = 0.001f, MW = 0.001f, SM = 0.001f, SUZ = 0.001f, SLZ = 0.001f;
        float rxP = 0.0f, k0P = 0.0f;

        const char* fbase = (const char*)forcing;
        const char* dbase = (const char*)dynr;
        const unsigned G12 = (unsigned)G * 12u;
        unsigned vRun = (unsigned)gc * 12u;          // row 0

        // depth-5 register ring: slots 0..4 = rows 0..4
        F3 bF[5], bD[5];
#pragma unroll
        for (int r = 0; r < 5; ++r) {
            bF[r] = ldo(fbase, vRun); bD[r] = ldo(dbase, vRun);
            vRun += G12;
        }                                            // vRun at row 5

        // prologue: ab(0) consumes slot 0 (row 0); restage row 5 -> slot 0
        {
            const F3 f_ = bF[0], d_ = bD[0];
            bF[0] = ldo(fbase, vRun); bD[0] = ldo(dbase, vRun);
            vRun += G12;
            __builtin_amdgcn_sched_barrier(0x7);
            ab_step0(f_, d_, pr, SP_, MW, SM, SLZ, rxP, k0P);
        }

        // step m: consume ring slot (m+1)%5 = (I+1)%5 (row m+1), stage row m+6.
#define W0(I, B, VOFF, DOLOAD) do { \
        constexpr int S_ = ((I) + 1) % 5; \
        const F3 f_ = bF[S_], d_ = bD[S_]; \
        if (DOLOAD) { bF[S_] = ldo(fbase, (VOFF)); bD[S_] = ldo(dbase, (VOFF)); } \
        __builtin_amdgcn_sched_barrier(0x7); \
        fused0<(I), (B)>(f_, d_, pr, SP_, MW, SM, SUZ, SLZ, rxP, k0P, qbuf, lane); \
} while (0)
#define W0ADV(I, B) do { W0(I, B, vRun, true); vRun += G12; } while (0)
#define W0G15(B) do { \
        W0ADV(0,B);  W0ADV(1,B);  W0ADV(2,B);  W0ADV(3,B);  W0ADV(4,B); \
        W0ADV(5,B);  W0ADV(6,B);  W0ADV(7,B);  W0ADV(8,B);  W0ADV(9,B); \
        W0ADV(10,B); W0ADV(11,B); W0ADV(12,B); W0ADV(13,B); W0ADV(14,B); \
} while (0)

        // groups j=0..21 (m=0..329; stages rows 6..335, all real)
        for (int jj = 0; jj < 11; ++jj) {
            W0G15(0);
            __syncthreads();                         // S(2jj+1)
            W0G15(1);
            __syncthreads();                         // S(2jj+2)
        }
        // j=22 (B=0): m=330..344, stages 336..350
        W0G15(0);
        __syncthreads();                             // S23
        // j=23 (B=1): m=345..358 stage 351..364; m=359 re-stages row 364
        W0ADV(0,1);  W0ADV(1,1);  W0ADV(2,1);  W0ADV(3,1);  W0ADV(4,1);
        W0ADV(5,1);  W0ADV(6,1);  W0ADV(7,1);  W0ADV(8,1);  W0ADV(9,1);
        W0ADV(10,1); W0ADV(11,1); W0ADV(12,1); W0ADV(13,1);
        W0(14, 1, (unsigned)gc * 12u + 364u * G12, true);
        __syncthreads();                             // S24
        // j=24 (B=0): m=360..364, no loads (ring holds rows 361..364 + dup)
        W0(0,0,0u,false); W0(1,0,0u,false); W0(2,0,0u,false);
        W0(3,0,0u,false); W0(4,0,0u,false);
        __syncthreads();                             // S25
        return;
#undef W0G15
#undef W0ADV
#undef W0
    }

    // ===== wave 1: FIR routing + stores =====
    {
        const float* sp = statr + (size_t)gc * 15;
        const float rout_a = sp[13] * 2.9f;
        const float rout_b = sp[14] * 6.5f;
        const float aa    = fmaxf(rout_a, 0.0f) + 0.1f;
        const float theta = fmaxf(rout_b, 0.0f) + 0.5f;
        const float am1   = aa - 1.0f;
        const float nitl2 = -LOG2E / theta;
        float w[RLEN];
        float wsum = 0.0f;
#pragma unroll
        for (int k = 0; k < RLEN; ++k) {
            const float tk = (float)k + 0.5f;
            w[k] = exp2f(am1 * __log2f(tk) + tk * nitl2);
            wsum += w[k];
        }
        const float winv = 1.0f / wsum;
#pragma unroll
        for (int k = 0; k < RLEN; ++k) w[k] *= winv;

        float acc[RLEN];
#pragma unroll
        for (int k = 0; k < RLEN; ++k) acc[k] = 0.0f;

        char* obase = (char*)out;
        const unsigned G4 = (unsigned)G * 4u;
        unsigned vO = (unsigned)g * 4u;
        const bool guard = (g < G);

        // FIR one group: slots 0..CNT-1 of buf B; out[m]=acc[i]+w0*Qs, scatter rest.
#define FIRG(B, CNT) do { \
        _Pragma("unroll") \
        for (int i = 0; i < (CNT); ++i) { \
            const float Qs = qbuf[B][i][lane]; \
            const float qr = fmaf(w[0], Qs, acc[i]); \
            acc[i] = 0.0f; \
            _Pragma("unroll") \
            for (int k = 1; k < RLEN; ++k) \
                acc[(i + k) % RLEN] = fmaf(w[k], Qs, acc[(i + k) % RLEN]); \
            if (guard) __builtin_nontemporal_store(qr, (float*)(obase + vO)); \
            vO += G4; \
        } \
} while (0)

        for (int jj = 0; jj < 11; ++jj) {
            __syncthreads();                         // S(2jj+1): group 2jj ready
            FIRG(0, RLEN);
            __syncthreads();                         // S(2jj+2)
            FIRG(1, RLEN);
        }
        __syncthreads();                             // S23: group 22 ready
        FIRG(0, RLEN);
        __syncthreads();                             // S24: group 23 ready
        FIRG(1, RLEN);
        __syncthreads();                             // S25: group 24 ready
        FIRG(0, 5);                                  // m=360..364
#undef FIRG
    }
}

extern "C" void kernel_launch(void* const* d_in, const int* in_sizes, int n_in,
                              void* d_out, int out_size, void* d_ws, size_t ws_size,
                              hipStream_t stream) {
    const float* forcing = (const float*)d_in[0];
    const float* dynr    = (const float*)d_in[1];
    const float* statr   = (const float*)d_in[2];
    float* out = (float*)d_out;

    const int G = in_sizes[2] / 15;          // static_raw (G,15); T fixed at 365
    const int block = 128;                   // wave0 = HBV spine, wave1 = FIR
    const int grid  = (G + 63) / 64;         // 64 cells per block
    hbv_kernel<<<grid, block, 0, stream>>>(forcing, dynr, statr, out, G);
}

// Round 21
// 98.030 us; speedup vs baseline: 1.2658x; 1.2658x over previous
//
#include <hip/hip_runtime.h>

#define NEARZERO 1e-5f
#define RLEN 15
#define LOG2E 1.4426950408889634f

struct __attribute__((packed, aligned(4))) F3 { float x, y, z; };
static __device__ __forceinline__ F3 ldo(const char* base, unsigned voff) {
    return *reinterpret_cast<const F3*>(base + voff);   // saddr + 32-bit voffset form
}

struct Par { float FC, invFC, invLPFC, K1, K2, PERC, UZL, TT, CFMAX, CFRC, CWH, C; };

// ---- prologue-only: snow+soil of t=0 ----
__device__ __forceinline__ void ab_step(
    const F3& f, const F3& d3, const Par& pr,
    float& SP, float& MW, float& SM, float& SLZ,
    float cs, float& rxP, float& k0P)
{
    const float pBETA   = fmaf(d3.x, 5.0f, 1.0f);
    const float pBETAET = fmaf(d3.z, 4.7f, 0.3f);
    const float dT   = f.y - pr.TT;
    const float RAIN = (dT >= 0.0f) ? f.x : 0.0f;
    SP += f.x - RAIN;
    const float melt = __builtin_amdgcn_fmed3f(pr.CFMAX * dT, 0.0f, SP);
    MW += melt;  SP -= melt;
    const float refr = __builtin_amdgcn_fmed3f(pr.CFRC * (0.0f - dT), 0.0f, MW);
    SP += refr;  MW -= refr;
    const float tosoil = fmaxf(fmaf(-pr.CWH, SP, MW), 0.0f);
    MW -= tosoil;
    const float sw = fminf(exp2f(pBETA * __log2f(SM * pr.invFC)), 1.0f);
    const float rt = RAIN + tosoil;
    const float rc = rt * sw;
    SM = fmaf(rt, 1.0f - sw, SM);
    const float ex = fmaxf(SM - pr.FC, 0.0f);
    SM = fminf(SM, pr.FC);
    const float ef = fminf(exp2f(pBETAET * __log2f(SM * pr.invLPFC)), 1.0f);
    SM = fmaxf(SM - f.z * ef, NEARZERO);
    const float cap = cs * (1.0f - fminf(SM * pr.invFC, 1.0f));
    SM  = fmaxf(SM + cap, NEARZERO);
    SLZ = fmaxf(SLZ - cap, NEARZERO);
    rxP = rc + ex;
    k0P = fmaf(d3.y, 0.85f, 0.05f);
}

// ---- fused: finish(m) [zones+FIR+store] hand-interleaved with ab(m+1),
//      ordered so every transcendental's latency is covered by independent work ----
template<int PH>
__device__ __forceinline__ void fused_iter(
    const F3 f, const F3 d3, const Par& pr,
    float& SP, float& MW, float& SM, float& SUZ, float& SLZ,
    float& rxP, float& k0P,
    float (&acc)[RLEN], const float (&w)[RLEN],
    float* outp, bool guard)
{
    // spine head of ab(m+1): SM(m) is ready NOW -> start trans #1 first
    const float t1 = __log2f(SM * pr.invFC);
    // snow of m+1 (independent; hides t1 latency)
    const float dT   = f.y - pr.TT;
    const float RAIN = (dT >= 0.0f) ? f.x : 0.0f;
    SP += f.x - RAIN;
    const float melt = __builtin_amdgcn_fmed3f(pr.CFMAX * dT, 0.0f, SP);
    MW += melt;  SP -= melt;
    const float refr = __builtin_amdgcn_fmed3f(pr.CFRC * (0.0f - dT), 0.0f, MW);
    SP += refr;  MW -= refr;
    const float tosoil = fmaxf(fmaf(-pr.CWH, SP, MW), 0.0f);
    MW -= tosoil;
    // finish(m) upper zone (independent)
    SUZ += rxP;
    const float PERCv = fminf(SUZ, pr.PERC);
    SUZ -= PERCv;
    const float Q0 = k0P * fmaxf(SUZ - pr.UZL, 0.0f);
    SUZ -= Q0;
    const float Q1 = pr.K1 * SUZ;
    SUZ -= Q1;
    // soil wetness (t1 long ready) -> trans #2; its latency hides under lower zone
    const float pBETA = fmaf(d3.x, 5.0f, 1.0f);
    const float sw = fminf(exp2f(pBETA * t1), 1.0f);
    const float rt = RAIN + tosoil;
    // finish(m) lower zone + Qs (independent of sw)
    SLZ += PERCv;
    const float Q2 = pr.K2 * SLZ;
    SLZ -= Q2;
    const float Qs = Q0 + Q1 + Q2;
    const float cs = pr.C * SLZ;                 // zones(m)-final SLZ -> capillary(m+1)
    // soil recharge/excess (sw ready)
    const float rc = rt * sw;
    SM = fmaf(rt, 1.0f - sw, SM);
    const float ex = fmaxf(SM - pr.FC, 0.0f);
    SM = fminf(SM, pr.FC);
    const float t2 = __log2f(SM * pr.invLPFC);   // trans #3; hidden by FIR below
    // FIR of m + store (15 independent FMAs fill t2's latency)
    const float qr = fmaf(w[0], Qs, acc[PH]);
    acc[PH] = 0.0f;
#pragma unroll
    for (int k = 1; k < RLEN; ++k) {
        const int j = (PH + k) % RLEN;           // compile-time
        acc[j] = fmaf(w[k], Qs, acc[j]);
    }
    if (guard) __builtin_nontemporal_store(qr, outp);
    // soil tail (trans #4 latency partially hidden by cs/cap prep)
    const float pBETAET = fmaf(d3.z, 4.7f, 0.3f);
    const float ef = fminf(exp2f(pBETAET * t2), 1.0f);
    SM = fmaxf(SM - f.z * ef, NEARZERO);
    const float cap = cs * (1.0f - fminf(SM * pr.invFC, 1.0f));   // cap <= SLZ (C<=1)
    SM  = fmaxf(SM + cap, NEARZERO);
    SLZ = fmaxf(SLZ - cap, NEARZERO);
    rxP = rc + ex;
    k0P = fmaf(d3.y, 0.85f, 0.05f);
}

// ---- final step's zones+FIR head+store only ----
template<int PH>
__device__ __forceinline__ void finish_step(
    const Par& pr, float& SUZ, float& SLZ, float rxP, float k0P,
    float (&acc)[RLEN], const float (&w)[RLEN], float* outp, bool guard)
{
    SUZ += rxP;
    const float PERCv = fminf(SUZ, pr.PERC);
    SUZ -= PERCv;
    const float Q0 = k0P * fmaxf(SUZ - pr.UZL, 0.0f);
    SUZ -= Q0;
    const float Q1 = pr.K1 * SUZ;
    SUZ -= Q1;
    SLZ += PERCv;
    const float Q2 = pr.K2 * SLZ;
    SLZ -= Q2;
    const float Qs = Q0 + Q1 + Q2;
    const float qr = fmaf(w[0], Qs, acc[PH]);
    if (guard) __builtin_nontemporal_store(qr, outp);
}

__global__ __launch_bounds__(256, 1)
void hbv_kernel(const float* __restrict__ forcing,   // (365,G,3)
                const float* __restrict__ dynr,      // (365,G,3)
                const float* __restrict__ statr,     // (G,15)
                float* __restrict__ out,             // (365,G)
                int G)
{
    const int g  = blockIdx.x * 256 + threadIdx.x;
    const int gc = (g < G) ? g : (G - 1);          // clamp for loads; store guarded
    const bool guard = (g < G);

    // ---- static parameters ----
    const float* sp = statr + (size_t)gc * 15;
    Par pr;
    pr.FC    = fmaf(sp[0], 950.0f, 50.0f);
    pr.K1    = fmaf(sp[1], 0.49f, 0.01f);
    pr.K2    = fmaf(sp[2], 0.199f, 0.001f);
    const float parLP = fmaf(sp[3], 0.8f, 0.2f);
    pr.PERC  = sp[4] * 10.0f;
    pr.UZL   = sp[5] * 100.0f;
    pr.TT    = fmaf(sp[6], 5.0f, -2.5f);
    pr.CFMAX = fmaf(sp[7], 9.5f, 0.5f);
    pr.CFRC  = (sp[8] * 0.1f) * pr.CFMAX;
    pr.CWH   = sp[9] * 0.2f;
    pr.C     = sp[10];
    const float rout_a = sp[13] * 2.9f;
    const float rout_b = sp[14] * 6.5f;
    pr.invFC   = 1.0f / pr.FC;
    pr.invLPFC = 1.0f / (parLP * pr.FC);

    // ---- routing weights (Gamma(aa)*theta^aa cancels in normalization) ----
    const float aa    = fmaxf(rout_a, 0.0f) + 0.1f;
    const float theta = fmaxf(rout_b, 0.0f) + 0.5f;
    const float am1   = aa - 1.0f;
    const float nitl2 = -LOG2E / theta;
    float w[RLEN];
    float wsum = 0.0f;
#pragma unroll
    for (int k = 0; k < RLEN; ++k) {
        const float tk = (float)k + 0.5f;
        w[k] = exp2f(am1 * __log2f(tk) + tk * nitl2);
        wsum += w[k];
    }
    const float winv = 1.0f / wsum;
#pragma unroll
    for (int k = 0; k < RLEN; ++k) w[k] *= winv;

    // ---- state ----
    float SP_ = 0.001f, MW = 0.001f, SM = 0.001f, SUZ = 0.001f, SLZ = 0.001f;
    float acc[RLEN];
#pragma unroll
    for (int k = 0; k < RLEN; ++k) acc[k] = 0.0f;
    float rxP = 0.0f, k0P = 0.0f;

    // ---- uniform-base + 32-bit voffset addressing ----
    const char* fbase = (const char*)forcing;
    const char* dbase = (const char*)dynr;
    char*       obase = (char*)out;
    const unsigned G12 = (unsigned)G * 12u;        // bytes per time row (streams)
    const unsigned G4  = (unsigned)G * 4u;         // bytes per time row (out)
    unsigned vRun = (unsigned)gc * 12u;            // row 0, this lane
    unsigned vO   = (unsigned)g  * 4u;             // out row 0 (g; OOB guarded)

    // ---- depth-5 register ring (5 | 15 -> slot = t % 5, constexpr) ----
    F3 bF[5], bD[5];
#pragma unroll
    for (int r = 0; r < 5; ++r) {
        bF[r] = ldo(fbase, vRun); bD[r] = ldo(dbase, vRun);
        vRun += G12;
    }                                               // vRun now at row 5

    // ---- prologue: snow+soil of t=0 (capillary uses initial SLZ) ----
    {
        const float cs0 = pr.C * SLZ;
        const F3 f_ = bF[0], d_ = bD[0];
        bF[0] = ldo(fbase, vRun); bD[0] = ldo(dbase, vRun);   // stage row 5 -> slot 0
        vRun += G12;
        __builtin_amdgcn_sched_barrier(0x7);        // pin VMEM; ALU may cross
        ab_step(f_, d_, pr, SP_, MW, SM, SLZ, cs0, rxP, k0P);
    }

#define ITER(MM, VOFF) do { \
    constexpr int PH_ = (MM) % RLEN; \
    constexpr int S_  = ((MM) + 1) % 5; \
    const F3 f_ = bF[S_], d_ = bD[S_]; \
    bF[S_] = ldo(fbase, (VOFF)); bD[S_] = ldo(dbase, (VOFF)); \
    __builtin_amdgcn_sched_barrier(0x7); \
    fused_iter<PH_>(f_, d_, pr, SP_, MW, SM, SUZ, SLZ, rxP, k0P, acc, w, \
                    (float*)(obase + vO), guard); \
    vO += G4; \
} while (0)

#define ITERADV(MM) do { ITER(MM, vRun); vRun += G12; } while (0)

#define ITER_NL(MM) do { \
    constexpr int PH_ = (MM) % RLEN; \
    constexpr int S_  = ((MM) + 1) % 5; \
    const F3 f_ = bF[S_], d_ = bD[S_]; \
    fused_iter<PH_>(f_, d_, pr, SP_, MW, SM, SUZ, SLZ, rxP, k0P, acc, w, \
                    (float*)(obase + vO), guard); \
    vO += G4; \
} while (0)

    // ---- main: m = 0..344 (23 x 15); stages rows 6..350 ----
    for (int i = 0; i < 23; ++i) {
        ITERADV(0);  ITERADV(1);  ITERADV(2);  ITERADV(3);  ITERADV(4);
        ITERADV(5);  ITERADV(6);  ITERADV(7);  ITERADV(8);  ITERADV(9);
        ITERADV(10); ITERADV(11); ITERADV(12); ITERADV(13); ITERADV(14);
    }
    // ---- penultimate: m = 345..358 stage rows 351..364; m=359 re-stages 364
    //      (its slot, step 365, is never consumed) ----
    ITERADV(0);  ITERADV(1);  ITERADV(2);  ITERADV(3);  ITERADV(4);
    ITERADV(5);  ITERADV(6);  ITERADV(7);  ITERADV(8);  ITERADV(9);
    ITERADV(10); ITERADV(11); ITERADV(12); ITERADV(13);
    ITER(14, (unsigned)gc * 12u + 364u * G12);     // m = 359
    // ---- epilogue: m = 360..363 consume rows 361..364 (already staged) ----
    ITER_NL(0); ITER_NL(1); ITER_NL(2); ITER_NL(3);
    // ---- final: finish(364), phase 364 % 15 = 4 ----
    finish_step<4>(pr, SUZ, SLZ, rxP, k0P, acc, w, (float*)(obase + vO), guard);
#undef ITER_NL
#undef ITERADV
#undef ITER
}

extern "C" void kernel_launch(void* const* d_in, const int* in_sizes, int n_in,
                              void* d_out, int out_size, void* d_ws, size_t ws_size,
                              hipStream_t stream) {
    const float* forcing = (const float*)d_in[0];
    const float* dynr    = (const float*)d_in[1];
    const float* statr   = (const float*)d_in[2];
    float* out = (float*)d_out;

    const int G = in_sizes[2] / 15;          // static_raw (G,15); T fixed at 365
    const int block = 256;
    const int grid  = (G + block - 1) / block;
    hbv_kernel<<<grid, block, 0, stream>>>(forcing, dynr, statr, out, G);
}